// Round 1
// 647.679 us; speedup vs baseline: 1.0070x; 1.0070x over previous
//
#include <hip/hip_runtime.h>
#include <math.h>

// Problem constants (B=4,S=1024 -> T=4096; D=2048; E=16; H=1024; top-2)
#define T_TOK 4096
#define DDIM  2048
#define HDIM  1024
#define NEXP  16
#define CAP   4096
#define GBM   128
#define GBN   128
#define GBK   64     // bf16 elems per K-tile
#define MAX_TILES 80 // sum ceil(cnt_e/128) <= 8192/128 + 16

typedef __attribute__((ext_vector_type(8))) short  short8;
typedef __attribute__((ext_vector_type(4))) float  floatx4;

__device__ __forceinline__ unsigned short f2bf(float f) {
    unsigned int u = __float_as_uint(f);
    u += 0x7fffu + ((u >> 16) & 1u);   // round-to-nearest-even
    return (unsigned short)(u >> 16);
}
__device__ __forceinline__ float bf2f(unsigned short u) {
    return __uint_as_float((unsigned int)u << 16);
}

__device__ __forceinline__ void gl_lds16(const void* g, void* l) {
    __builtin_amdgcn_global_load_lds(
        (const __attribute__((address_space(1))) unsigned int*)g,
        (__attribute__((address_space(3))) unsigned int*)l,
        16, 0, 0);
}

// ---------------------------------------------------------------------------
// prep_kernel v2: grid (136, 1, 32).
//   bid<128 : weight transpose tile [k=256][n=64] for W1 (z<16) / W2 (z>=16)
//             reg-level 4x4 transpose -> XOR-swizzled LDS granules
//             (conflict-free both sides) -> 512-B-per-row output stores.
//   bid>=128: gating, 16 tokens/block (interleaved with transpose across z,
//             no tail phase).
// ---------------------------------------------------------------------------
__global__ __launch_bounds__(256) void prep_kernel(
    const float* __restrict__ x, const float* __restrict__ Wg,
    const float* __restrict__ bias,
    const float* __restrict__ W1, const float* __restrict__ W2,
    unsigned short* __restrict__ W1T, unsigned short* __restrict__ W2T,
    int* __restrict__ counts, int* __restrict__ tok_list,
    int4* __restrict__ tinfo, float2* __restrict__ wcomb,
    unsigned short* __restrict__ xbf)
{
    // granule layout: [n=64 rows][64 granules of 4 k-elems], granule slot
    // g' = g ^ (n & 14)  (even mask keeps 16-B granule-pairs order-intact)
    __shared__ __align__(16) unsigned short Ls[64 * 256];   // 32 KB
    int z   = blockIdx.z;
    int bid = blockIdx.x;
    int tid = threadIdx.x;

    if (bid < 128) {
        // ---- weight convert+transpose to bf16 [e][n][k] ----
        const float* src; unsigned short* dst; int K, N, kt, nt;
        if (z < NEXP) {
            K = DDIM; N = HDIM;                       // W1: [d][h] -> [h][d]
            src = W1 + (size_t)z * K * N;
            dst = W1T + (size_t)z * (size_t)N * K;
            kt = bid >> 4; nt = bid & 15;             // 8 x 16
        } else {
            K = HDIM; N = DDIM;                       // W2: [h][d] -> [d][h]
            src = W2 + (size_t)(z - NEXP) * K * N;
            dst = W2T + (size_t)(z - NEXP) * (size_t)N * K;
            kt = bid >> 5; nt = bid & 31;             // 4 x 32
        }
        int kb = kt * 256, nb = nt * 64;
        int r = tid >> 4;          // 0..15  (k-granule within 64-row subtile)
        int c16 = tid & 15;        // n-granule
        const float* s0 = src + (size_t)kb * N + nb + c16 * 4;

#pragma unroll
        for (int i4 = 0; i4 < 4; ++i4) {
            float4 v[4];
#pragma unroll
            for (int i = 0; i < 4; ++i)
                v[i] = *(const float4*)(s0 + (size_t)(i4 * 64 + r * 4 + i) * N);
#pragma unroll
            for (int j = 0; j < 4; ++j) {
                unsigned int lo = (unsigned int)f2bf(((const float*)&v[0])[j])
                                | ((unsigned int)f2bf(((const float*)&v[1])[j]) << 16);
                unsigned int hi = (unsigned int)f2bf(((const float*)&v[2])[j])
                                | ((unsigned int)f2bf(((const float*)&v[3])[j]) << 16);
                int n  = c16 * 4 + j;
                int g  = i4 * 16 + r;                 // k-granule 0..63
                int gp = g ^ (n & 14);
                *(uint2*)&Ls[n * 256 + gp * 4] = make_uint2(lo, hi);
            }
        }
        __syncthreads();
        unsigned short* d0 = dst + (size_t)nb * K + kb;
#pragma unroll
        for (int j = 0; j < 8; ++j) {
            int c = tid + j * 256;
            int n = c >> 5, a = c & 31;               // granule-pair a
            int sp = (2 * a) ^ (n & 14);              // even -> aligned pair
            short8 sv = *(const short8*)&Ls[n * 256 + sp * 4];
            *(short8*)(d0 + (size_t)n * K + a * 8) = sv;
        }
        return;
    }

    // ---- gating: 4 waves/block, 4 tokens/wave (sequential) ----
    int gb   = z * 8 + (bid - 128);                   // 0..255
    int wv   = tid >> 6;
    int lane = tid & 63;
    const float4* wg4 = (const float4*)Wg;

    for (int tk = 0; tk < 4; ++tk) {
        int t = gb * 16 + wv * 4 + tk;

        const float4* xp4 = (const float4*)x + (size_t)t * (DDIM / 4);
        ushort4* xbp4 = (ushort4*)(xbf + (size_t)t * DDIM);

        float acc[NEXP];
#pragma unroll
        for (int e = 0; e < NEXP; ++e) acc[e] = 0.f;

        for (int it = 0; it < DDIM / 4 / 64; ++it) {
            int d4 = it * 64 + lane;
            float4 xv = xp4[d4];
            ushort4 xs;
            xs.x = f2bf(xv.x); xs.y = f2bf(xv.y);
            xs.z = f2bf(xv.z); xs.w = f2bf(xv.w);
            xbp4[d4] = xs;
#pragma unroll
            for (int e = 0; e < NEXP; ++e) {
                float4 wvv = wg4[e * (DDIM / 4) + d4];
                acc[e] += xv.x * wvv.x + xv.y * wvv.y + xv.z * wvv.z + xv.w * wvv.w;
            }
        }
#pragma unroll
        for (int e = 0; e < NEXP; ++e) {
            float v = acc[e];
#pragma unroll
            for (int off = 32; off > 0; off >>= 1) v += __shfl_xor(v, off, 64);
            acc[e] = v;
        }
        if (lane == 0) {
            float s[NEXP];
#pragma unroll
            for (int e = 0; e < NEXP; ++e)
                s[e] = 1.f / (1.f + expf(-(acc[e] + bias[e])));
            int i0 = 0;
#pragma unroll
            for (int e = 1; e < NEXP; ++e) if (s[e] > s[i0]) i0 = e;
            int i1 = (i0 == 0) ? 1 : 0;
            for (int e = 0; e < NEXP; ++e)
                if (e != i0 && s[e] > s[i1]) i1 = e;
            float denom = s[i0] + s[i1] + 1e-6f;
            int p0 = atomicAdd(&counts[i0], 1);
            tok_list[i0 * CAP + p0] = t;
            int p1 = atomicAdd(&counts[i1], 1);
            tok_list[i1 * CAP + p1] = t;
            tinfo[t] = make_int4(i0, p0, i1, p1);
            wcomb[t] = make_float2(s[i0] / denom, s[i1] / denom);
        }
    }
}

// ---------------------------------------------------------------------------
// scan v2: single wave, shuffle prefix-scan (no serial dependent-load chain).
// ---------------------------------------------------------------------------
__global__ void scan_kernel(const int* __restrict__ counts, int* __restrict__ offsets,
                            int* __restrict__ ntiles, int* __restrict__ tile_e,
                            int* __restrict__ tile_mt)
{
    int lane = threadIdx.x;                         // 64 threads
    int c = (lane < NEXP) ? counts[lane] : 0;
    int incl = c;
#pragma unroll
    for (int d = 1; d < 64; d <<= 1) {
        int v = __shfl_up(incl, d, 64);
        if (lane >= d) incl += v;
    }
    if (lane < NEXP) offsets[lane] = incl - c;
    if (lane == NEXP - 1) offsets[NEXP] = incl;

    int nt_e = (lane < NEXP) ? ((c + GBM - 1) / GBM) : 0;
    int tincl = nt_e;
#pragma unroll
    for (int d = 1; d < 64; d <<= 1) {
        int v = __shfl_up(tincl, d, 64);
        if (lane >= d) tincl += v;
    }
    int tbase = tincl - nt_e;
    if (lane < NEXP) {
        for (int i = 0; i < nt_e; ++i) {
            tile_e[tbase + i]  = lane;
            tile_mt[tbase + i] = i;
        }
        if (lane == NEXP - 1) *ntiles = tbase + nt_e;
    }
}

// ---------------------------------------------------------------------------
// up_gemm: h = silu(Xg @ W1T^T) -> bf16 hbuf. 128x128x64 tiles, ping-pong
// LDS dbuf, global_load_lds(16B), XOR chunk swizzle.
// ---------------------------------------------------------------------------
__global__ __launch_bounds__(256) void up_gemm(
    const unsigned short* __restrict__ xbf, const unsigned short* __restrict__ W1T,
    const int* __restrict__ counts, const int* __restrict__ offsets,
    const int* __restrict__ ntiles, const int* __restrict__ tile_e,
    const int* __restrict__ tile_mt,
    const int* __restrict__ tok_list, unsigned short* __restrict__ hbuf)
{
    int idx = blockIdx.x;
    if (idx >= *ntiles) return;
    int e   = tile_e[idx];
    int mt  = tile_mt[idx];
    int cnt = counts[e];
    int nbase = blockIdx.y * GBN;

    __shared__ __align__(16) unsigned short As[2][GBM * GBK];
    __shared__ __align__(16) unsigned short Bs[2][GBN * GBK];

    int tid = threadIdx.x, lane = tid & 63, wv = tid >> 6;
    int kcL = ((lane & 7) ^ ((lane >> 3) & 7)) * 8;
    int hbase = offsets[e];

    const unsigned short* gA[4];
    const unsigned short* gB[4];
#pragma unroll
    for (int j = 0; j < 4; ++j) {
        int row = wv * 32 + j * 8 + (lane >> 3);
        int m = mt * GBM + row; if (m >= cnt) m = cnt - 1;
        int tok = tok_list[e * CAP + m];
        gA[j] = xbf + (size_t)tok * DDIM + kcL;
        gB[j] = W1T + ((size_t)e * HDIM + nbase + row) * DDIM + kcL;
    }
    int fr = lane & 15, fq = lane >> 4;
    int wm = (wv & 1) * 64, wn = (wv >> 1) * 64;

    floatx4 acc[4][4];
#pragma unroll
    for (int i = 0; i < 4; ++i)
#pragma unroll
        for (int j = 0; j < 4; ++j) acc[i][j] = (floatx4){0.f, 0.f, 0.f, 0.f};

#pragma unroll
    for (int j = 0; j < 4; ++j)
        gl_lds16(gA[j], &As[0][((wv * 4 + j) * 64 + lane) * 8]);
#pragma unroll
    for (int j = 0; j < 4; ++j)
        gl_lds16(gB[j], &Bs[0][((wv * 4 + j) * 64 + lane) * 8]);

    const int NK = DDIM / GBK;
    for (int i = 0; i < NK; ++i) {
        int cur = i & 1, nxt = cur ^ 1;
        __syncthreads();
        if (i + 1 < NK) {
            int k0 = (i + 1) * GBK;
#pragma unroll
            for (int j = 0; j < 4; ++j)
                gl_lds16(gA[j] + k0, &As[nxt][((wv * 4 + j) * 64 + lane) * 8]);
#pragma unroll
            for (int j = 0; j < 4; ++j)
                gl_lds16(gB[j] + k0, &Bs[nxt][((wv * 4 + j) * 64 + lane) * 8]);
        }
#pragma unroll
        for (int ks = 0; ks < 2; ++ks) {
            short8 af[4], bfr[4];
#pragma unroll
            for (int mi = 0; mi < 4; ++mi) {
                int row = wm + mi * 16 + fr;
                int kcs = (ks * 4 + fq) ^ (row & 7);
                af[mi] = *(const short8*)&As[cur][row * GBK + kcs * 8];
            }
#pragma unroll
            for (int ni = 0; ni < 4; ++ni) {
                int row = wn + ni * 16 + fr;
                int kcs = (ks * 4 + fq) ^ (row & 7);
                bfr[ni] = *(const short8*)&Bs[cur][row * GBK + kcs * 8];
            }
#pragma unroll
            for (int mi = 0; mi < 4; ++mi)
#pragma unroll
                for (int ni = 0; ni < 4; ++ni)
                    acc[mi][ni] = __builtin_amdgcn_mfma_f32_16x16x32_bf16(
                        af[mi], bfr[ni], acc[mi][ni], 0, 0, 0);
        }
    }

#pragma unroll
    for (int mi = 0; mi < 4; ++mi) {
#pragma unroll
        for (int r = 0; r < 4; ++r) {
            int row = wm + mi * 16 + fq * 4 + r;
            int m = mt * GBM + row;
            if (m < cnt) {
                size_t ro = (size_t)(hbase + m) * HDIM + nbase + wn;
#pragma unroll
                for (int ni = 0; ni < 4; ++ni) {
                    float u  = acc[mi][ni][r];
                    float hh = u / (1.f + __expf(-u));     // silu
                    hbuf[ro + ni * 16 + fr] = f2bf(hh);
                }
            }
        }
    }
}

// ---------------------------------------------------------------------------
// down_gemm: y = h @ W2T^T -> bf16 ybuf (plain stores, no atomics).
// ---------------------------------------------------------------------------
__global__ __launch_bounds__(256) void down_gemm(
    const unsigned short* __restrict__ hbuf, const unsigned short* __restrict__ W2T,
    const int* __restrict__ counts, const int* __restrict__ offsets,
    const int* __restrict__ ntiles, const int* __restrict__ tile_e,
    const int* __restrict__ tile_mt,
    unsigned short* __restrict__ ybuf)
{
    int idx = blockIdx.x;
    if (idx >= *ntiles) return;
    int e   = tile_e[idx];
    int mt  = tile_mt[idx];
    int cnt = counts[e];
    int nbase = blockIdx.y * GBN;

    __shared__ __align__(16) unsigned short As[2][GBM * GBK];
    __shared__ __align__(16) unsigned short Bs[2][GBN * GBK];

    int tid = threadIdx.x, lane = tid & 63, wv = tid >> 6;
    int kcL = ((lane & 7) ^ ((lane >> 3) & 7)) * 8;
    int hbase = offsets[e];

    const unsigned short* gA[4];
    const unsigned short* gB[4];
#pragma unroll
    for (int j = 0; j < 4; ++j) {
        int row = wv * 32 + j * 8 + (lane >> 3);
        int m = mt * GBM + row; if (m >= cnt) m = cnt - 1;
        gA[j] = hbuf + (size_t)(hbase + m) * HDIM + kcL;
        gB[j] = W2T + ((size_t)e * DDIM + nbase + row) * HDIM + kcL;
    }
    int fr = lane & 15, fq = lane >> 4;
    int wm = (wv & 1) * 64, wn = (wv >> 1) * 64;

    floatx4 acc[4][4];
#pragma unroll
    for (int i = 0; i < 4; ++i)
#pragma unroll
        for (int j = 0; j < 4; ++j) acc[i][j] = (floatx4){0.f, 0.f, 0.f, 0.f};

#pragma unroll
    for (int j = 0; j < 4; ++j)
        gl_lds16(gA[j], &As[0][((wv * 4 + j) * 64 + lane) * 8]);
#pragma unroll
    for (int j = 0; j < 4; ++j)
        gl_lds16(gB[j], &Bs[0][((wv * 4 + j) * 64 + lane) * 8]);

    const int NK = HDIM / GBK;
    for (int i = 0; i < NK; ++i) {
        int cur = i & 1, nxt = cur ^ 1;
        __syncthreads();
        if (i + 1 < NK) {
            int k0 = (i + 1) * GBK;
#pragma unroll
            for (int j = 0; j < 4; ++j)
                gl_lds16(gA[j] + k0, &As[nxt][((wv * 4 + j) * 64 + lane) * 8]);
#pragma unroll
            for (int j = 0; j < 4; ++j)
                gl_lds16(gB[j] + k0, &Bs[nxt][((wv * 4 + j) * 64 + lane) * 8]);
        }
#pragma unroll
        for (int ks = 0; ks < 2; ++ks) {
            short8 af[4], bfr[4];
#pragma unroll
            for (int mi = 0; mi < 4; ++mi) {
                int row = wm + mi * 16 + fr;
                int kcs = (ks * 4 + fq) ^ (row & 7);
                af[mi] = *(const short8*)&As[cur][row * GBK + kcs * 8];
            }
#pragma unroll
            for (int ni = 0; ni < 4; ++ni) {
                int row = wn + ni * 16 + fr;
                int kcs = (ks * 4 + fq) ^ (row & 7);
                bfr[ni] = *(const short8*)&Bs[cur][row * GBK + kcs * 8];
            }
#pragma unroll
            for (int mi = 0; mi < 4; ++mi)
#pragma unroll
                for (int ni = 0; ni < 4; ++ni)
                    acc[mi][ni] = __builtin_amdgcn_mfma_f32_16x16x32_bf16(
                        af[mi], bfr[ni], acc[mi][ni], 0, 0, 0);
        }
    }

#pragma unroll
    for (int mi = 0; mi < 4; ++mi) {
#pragma unroll
        for (int r = 0; r < 4; ++r) {
            int row = wm + mi * 16 + fq * 4 + r;
            int m = mt * GBM + row;
            if (m < cnt) {
                size_t ro = (size_t)(hbase + m) * DDIM + nbase + wn;
#pragma unroll
                for (int ni = 0; ni < 4; ++ni)
                    ybuf[ro + ni * 16 + fr] = f2bf(acc[mi][ni][r]);
            }
        }
    }
}

// ---------------------------------------------------------------------------
// combine: out[t] = w0 * y[slot0] + w1 * y[slot1]  (writes every element,
// so no out-memset needed).
// ---------------------------------------------------------------------------
__global__ __launch_bounds__(256) void combine_kernel(
    const unsigned short* __restrict__ ybuf, const int* __restrict__ offsets,
    const int4* __restrict__ tinfo, const float2* __restrict__ wcomb,
    float* __restrict__ out)
{
    int t = blockIdx.x;
    int4   ti = tinfo[t];
    float2 w  = wcomb[t];
    int s0 = offsets[ti.x] + ti.y;
    int s1 = offsets[ti.z] + ti.w;
    const ushort4* y0 = (const ushort4*)(ybuf + (size_t)s0 * DDIM);
    const ushort4* y1 = (const ushort4*)(ybuf + (size_t)s1 * DDIM);
    float4* op = (float4*)(out + (size_t)t * DDIM);
#pragma unroll
    for (int i = 0; i < 2; ++i) {
        int c = threadIdx.x + i * 256;
        ushort4 a = y0[c], b = y1[c];
        float4 r;
        r.x = w.x * bf2f(a.x) + w.y * bf2f(b.x);
        r.y = w.x * bf2f(a.y) + w.y * bf2f(b.y);
        r.z = w.x * bf2f(a.z) + w.y * bf2f(b.z);
        r.w = w.x * bf2f(a.w) + w.y * bf2f(b.w);
        op[c] = r;
    }
}

// ---------------------------------------------------------------------------
// Workspace layout (bytes):
//   0         counts[16]
//   256       offsets[17]
//   512       ntiles + tile_e[80] + tile_mt[80]
//   2048      tok_list 16*4096*4      = 256 KB
//   264192    tinfo    4096*16        = 64 KB
//   329728    wcomb    4096*8         = 32 KB
//   524288    xbf      4096*2048*2    = 16 MB
//   17301504  hbuf     8192*1024*2    = 16 MB
//   34078720  ybuf     8192*2048*2    = 32 MB
//   67633152  W1T      16*1024*2048*2 = 64 MB
//   134742016 W2T      16*2048*1024*2 = 64 MB  -> total ~192.5 MB
// ---------------------------------------------------------------------------
extern "C" void kernel_launch(void* const* d_in, const int* in_sizes, int n_in,
                              void* d_out, int out_size, void* d_ws, size_t ws_size,
                              hipStream_t stream)
{
    const float* x    = (const float*)d_in[0];
    const float* Wg   = (const float*)d_in[1];
    const float* bias = (const float*)d_in[2];
    const float* W1   = (const float*)d_in[3];
    const float* W2   = (const float*)d_in[4];
    float* out = (float*)d_out;

    char* ws = (char*)d_ws;
    int*            counts   = (int*)(ws + 0);
    int*            offsets  = (int*)(ws + 256);
    int*            ntiles   = (int*)(ws + 512);
    int*            tile_e   = (int*)(ws + 512 + 4);
    int*            tile_mt  = (int*)(ws + 512 + 4 + MAX_TILES * 4);
    int*            tok_list = (int*)(ws + 2048);
    int4*           tinfo    = (int4*)(ws + 264192);
    float2*         wcomb    = (float2*)(ws + 329728);
    unsigned short* xbf      = (unsigned short*)(ws + 524288);
    unsigned short* hbuf     = (unsigned short*)(ws + 17301504);
    unsigned short* ybuf     = (unsigned short*)(ws + 34078720);
    unsigned short* W1T      = (unsigned short*)(ws + 67633152);
    unsigned short* W2T      = (unsigned short*)(ws + 134742016);

    hipMemsetAsync(counts, 0, 64, stream);

    prep_kernel<<<dim3(136, 1, 32), 256, 0, stream>>>(
        x, Wg, bias, W1, W2, W1T, W2T, counts, tok_list, tinfo, wcomb, xbf);
    scan_kernel<<<1, 64, 0, stream>>>(counts, offsets, ntiles, tile_e, tile_mt);
    up_gemm<<<dim3(MAX_TILES, HDIM / GBN), 256, 0, stream>>>(
        xbf, W1T, counts, offsets, ntiles, tile_e, tile_mt, tok_list, hbuf);
    down_gemm<<<dim3(MAX_TILES, DDIM / GBN), 256, 0, stream>>>(
        hbuf, W2T, counts, offsets, ntiles, tile_e, tile_mt, ybuf);
    combine_kernel<<<T_TOK, 256, 0, stream>>>(ybuf, offsets, tinfo, wcomb, out);
}